// Round 5
// baseline (1407.291 us; speedup 1.0000x reference)
//
#include <hip/hip_runtime.h>
#include <hip/hip_bf16.h>

// GCN: x=emb[ids]; x1=relu(GCNConv(x,W1,b1)); y=Ahat@x1; out[g]=b2+(mean_g y)@W2
// Ahat = sym-normalized adjacency with self loops (norm = dinv[src]*dinv[dst]).
//
// Restructuring:
//  - conv1: rank-17 input -> h1=(emb@W1)[type]; neighbor sum factors through
//    17 type bins C[i][t] (edge-parallel atomics), then dense 17-term FMA.
//  - conv2 commutes with @W2 and mean-pool -> only poolY[64][128] is needed.
//  - R4: NO CSR. conv2 is edge-parallel with a per-block LDS accumulator
//    (64 graphs x 128 feat fp32 = 32 KB), one edge per wave: gather 256 B
//    bf16 x1 row + 2 stride-1 ds_add_f32. Self loops = N virtual edges.
//    (kills k_fill: 101 MB write-amplified scatter, 93 us; and the scans.)
//  - R1: graph counts via binary search on sorted batch.
//  - R2: x1 stored bf16; lane holds features {lane, lane+64} (conflict-free).

#define DDIM 128
#define CPAD 20   // C row stride (17 used, padded for 16B-aligned float4 reads)
typedef unsigned int uint;

__device__ __forceinline__ float bflo(uint v) { return __uint_as_float(v << 16); }
__device__ __forceinline__ float bfhi(uint v) { return __uint_as_float(v & 0xffff0000u); }
__device__ __forceinline__ uint packbf(float x, float y) {  // RNE round both
    uint ux = __float_as_uint(x), uy = __float_as_uint(y);
    ux = (ux + 0x7fff + ((ux >> 16) & 1)) >> 16;
    uy = (uy + 0x7fff + ((uy >> 16) & 1)) & 0xffff0000u;
    return ux | uy;
}

__global__ void k_deg(const int* __restrict__ dst, int* __restrict__ deg, int E) {
    int i = blockIdx.x * blockDim.x + threadIdx.x;
    int stride = gridDim.x * blockDim.x;
    for (int e = i; e < E; e += stride) atomicAdd(&deg[dst[e]], 1);
}

// batch is sorted: cnt[g] = lower_bound(g+1) - lower_bound(g). No atomics.
__global__ void k_cnt(const int* __restrict__ batch, int* __restrict__ cnt,
                      int N, int G) {
    int g = threadIdx.x;
    if (g >= G) return;
    auto lb = [&](int key) {
        int lo = 0, hi = N;
        while (lo < hi) {
            int mid = (lo + hi) >> 1;
            if (batch[mid] < key) lo = mid + 1; else hi = mid;
        }
        return lo;
    };
    cnt[g] = lb(g + 1) - lb(g);
}

// nd[i] = {dinv_i, type_i bits}; deg is edge-only indegree, +1 self loop.
__global__ void k_pack(const int* __restrict__ deg, const int* __restrict__ ids,
                       float2* __restrict__ nd, int N) {
    int i = blockIdx.x * blockDim.x + threadIdx.x;
    if (i < N) {
        float dinv = rsqrtf((float)(deg[i] + 1));
        nd[i] = make_float2(dinv, __int_as_float(ids[i]));
    }
}

// C[dst][type_src] += dinv_src  (edge-parallel, scalar fp32 atomics over 8 MB)
__global__ void k_bin(const int* __restrict__ src, const int* __restrict__ dst,
                      const float2* __restrict__ nd, float* __restrict__ C, int E) {
    int i = blockIdx.x * blockDim.x + threadIdx.x;
    int stride = gridDim.x * blockDim.x;
    for (int e = i; e < E; e += stride) {
        int s = src[e];
        int d = dst[e];
        float2 ns = nd[s];
        atomicAdd(&C[d * CPAD + __float_as_int(ns.y)], ns.x);
    }
}

// t1 = emb @ W1  (17 x 128)
__global__ void k_t1(const float* __restrict__ emb, const float* __restrict__ W1,
                     float* __restrict__ t1) {
    int t = blockIdx.x, f = threadIdx.x;
    float acc = 0.f;
    for (int k = 0; k < DDIM; k++) acc += emb[t * DDIM + k] * W1[k * DDIM + f];
    t1[t * DDIM + f] = acc;
}

// x1[i] = relu(b1 + dinv_i*(sum_t C[i][t]*t1[t] + dinv_i*t1[ti]))  -> bf16x2
// Lane holds features {lane, lane+64} packed as {lo, hi}. 4 waves/block.
__global__ void __launch_bounds__(256) k_x1(
        const float2* __restrict__ nd, const float* __restrict__ C,
        const float* __restrict__ t1, const float* __restrict__ b1,
        uint* __restrict__ x1u, int N) {
    int lane = threadIdx.x & 63, wave = threadIdx.x >> 6;
    int i = blockIdx.x * 4 + wave;
    if (i >= N) return;
    float2 ndi = nd[i];
    float dinv_i = ndi.x;
    int ti = __float_as_int(ndi.y);
    const float4* Cv = (const float4*)(C + i * CPAD);
    float4 c0 = Cv[0], c1 = Cv[1], c2 = Cv[2], c3 = Cv[3];
    float c16 = C[i * CPAD + 16];
    float cc[17] = {c0.x, c0.y, c0.z, c0.w, c1.x, c1.y, c1.z, c1.w,
                    c2.x, c2.y, c2.z, c2.w, c3.x, c3.y, c3.z, c3.w, c16};
    float ax = dinv_i * t1[ti * DDIM + lane];          // self loop
    float ay = dinv_i * t1[ti * DDIM + 64 + lane];
#pragma unroll
    for (int t = 0; t < 17; t++) {
        ax += cc[t] * t1[t * DDIM + lane];
        ay += cc[t] * t1[t * DDIM + 64 + lane];
    }
    float vx = b1[lane]      + dinv_i * ax;
    float vy = b1[64 + lane] + dinv_i * ay;
    vx = vx > 0.f ? vx : 0.f;
    vy = vy > 0.f ? vy : 0.f;
    x1u[i * 64 + lane] = packbf(vx, vy);
}

// Edge-parallel conv2+pool: item space = E edges + N self loops.
// Per block: private fp32 acc[64][128] in LDS; one item per wave per step;
// metadata staged 64-wide coalesced into per-wave LDS scratch.
__global__ void __launch_bounds__(256) k_conv2e(
        const int* __restrict__ src, const int* __restrict__ dst,
        const int* __restrict__ batch, const float2* __restrict__ nd,
        const uint* __restrict__ x1u, float* __restrict__ poolY,
        int E, int N) {
    __shared__ float acc[64 * DDIM];       // 32 KB graph accumulator
    __shared__ float4 meta[4][64];         // per-wave item scratch
    int t = threadIdx.x;
    for (int k = t; k < 64 * DDIM; k += 256) acc[k] = 0.f;
    __syncthreads();

    int lane = t & 63, wave = t >> 6;
    int M = E + N;
    int totalWaves = gridDim.x * 4;
    for (int base = (blockIdx.x * 4 + wave) * 64; base < M; base += totalWaves * 64) {
        int item = base + lane;
        int s = 0, g = 0; float w = 0.f;
        if (item < E) {                    // real edge
            s = src[item];
            int d = dst[item];
            w = nd[s].x * nd[d].x;
            g = batch[d];
        } else if (item < M) {             // self loop of node i
            int i = item - E;
            s = i;
            float di = nd[i].x;
            w = di * di;
            g = batch[i];
        }
        meta[wave][lane] = make_float4(__int_as_float(s), w, __int_as_float(g), 0.f);
        int nItems = M - base; if (nItems > 64) nItems = 64;
        for (int j = 0; j < nItems; j++) { // wave-uniform broadcast from LDS
            float4 m = meta[wave][j];
            int sj = __float_as_int(m.x);
            float wj = m.y;
            int gj = __float_as_int(m.z);
            uint v = x1u[sj * 64 + lane];  // coalesced 256 B row gather
            atomicAdd(&acc[gj * DDIM + lane],      wj * bflo(v));
            atomicAdd(&acc[gj * DDIM + 64 + lane], wj * bfhi(v));
        }
    }
    __syncthreads();
    for (int k = t; k < 64 * DDIM; k += 256) atomicAdd(&poolY[k], acc[k]);
}

// out[g] = b2 + (poolY[g]/cnt[g]) @ W2 ; cnt==0 -> 0
__global__ void k_out(const float* __restrict__ poolY, const int* __restrict__ cnt,
                      const float* __restrict__ W2, const float* __restrict__ b2,
                      float* __restrict__ out) {
    int g = blockIdx.x, f = threadIdx.x;
    float acc = 0.f;
    for (int k = 0; k < DDIM; k++) acc += poolY[g * DDIM + k] * W2[k * DDIM + f];
    int c = cnt[g];
    out[g * DDIM + f] = (c > 0) ? (b2[f] + acc / (float)c) : 0.f;
}

extern "C" void kernel_launch(void* const* d_in, const int* in_sizes, int n_in,
                              void* d_out, int out_size, void* d_ws, size_t ws_size,
                              hipStream_t stream) {
    const int* node_ids = (const int*)d_in[0];
    const int* edge_index = (const int*)d_in[1];
    const int* batch = (const int*)d_in[2];
    const float* emb = (const float*)d_in[4];
    const float* W1 = (const float*)d_in[5];
    const float* b1 = (const float*)d_in[6];
    const float* W2 = (const float*)d_in[7];
    const float* b2 = (const float*)d_in[8];
    float* out = (float*)d_out;

    const int N = in_sizes[0];
    const int E = in_sizes[1] / 2;
    const int G = out_size / DDIM;
    const int* src = edge_index;
    const int* dst = edge_index + E;

    char* ws = (char*)d_ws;
    size_t off = 0;
    auto carve = [&](size_t bytes) { char* p = ws + off; off = (off + bytes + 255) & ~size_t(255); return p; };
    uint*   x1u   = (uint*)carve((size_t)N * 64 * 4);      // bf16x2 packed
    float*  C     = (float*)carve((size_t)N * CPAD * 4);   // type bins
    float2* nd    = (float2*)carve((size_t)N * 8);
    int*    deg   = (int*)carve((size_t)N * 4);
    float*  t1    = (float*)carve(17 * DDIM * 4);
    float*  poolY = (float*)carve((size_t)G * DDIM * 4);
    int*    cnt   = (int*)carve((size_t)G * 4);

    hipMemsetAsync(deg,   0, (size_t)N * 4, stream);
    hipMemsetAsync(C,     0, (size_t)N * CPAD * 4, stream);
    hipMemsetAsync(poolY, 0, (size_t)G * DDIM * 4, stream);

    k_deg<<<2048, 256, 0, stream>>>(dst, deg, E);
    k_cnt<<<1, 64, 0, stream>>>(batch, cnt, N, G);
    k_pack<<<(N + 255) / 256, 256, 0, stream>>>(deg, node_ids, nd, N);
    k_bin<<<2048, 256, 0, stream>>>(src, dst, nd, C, E);

    k_t1<<<17, DDIM, 0, stream>>>(emb, W1, t1);
    k_x1<<<(N + 3) / 4, 256, 0, stream>>>(nd, C, t1, b1, x1u, N);
    k_conv2e<<<1024, 256, 0, stream>>>(src, dst, batch, nd, x1u, poolY, E, N);
    k_out<<<G, DDIM, 0, stream>>>(poolY, cnt, W2, b2, out);
}